// Round 10
// baseline (138.701 us; speedup 1.0000x reference)
//
#include <hip/hip_runtime.h>

// SNN excitatory layer only (inhibitory layer never affects the returned
// spikes — the scan discards its carry).
//
// R9: column-sliced block — 4 waves x 4 neurons; wave wid owns columns
// [wid*512, wid*512+512) of ALL 4 neuron rows.
//  - Evidence R5/R7: bound by moving 8 KB of x per wave per step through
//    L1 (~64B/cy/CU) or LDS (~85-128B/cy/CU) — both ~1000 cy/step/CU.
//    Slicing cuts per-wave x bytes 4x (2 KB/step; 16 KB/CU/step ~ 256 cy).
//  - per-wave FMA work unchanged (4 neurons x 8-elem dot + 32-elem STDP).
//  - partial sums exchanged via 16-float LDS buffer, double-buffered, one
//    barrier/step; partial(t) consumed at t+1's syn update (R3 insight) ->
//    reduce+ds_write issue after the dot, latency hides under STDP.
//  - x register ping-pong, one row ahead; t_pre slice loaded on spike steps.
//  - per-neuron arithmetic sequence unchanged -> spike-exact.

constexpr int T_STEPS = 128;
constexpr int N_IN    = 2048;
constexpr int N_EXC   = 2048;
constexpr int SLICE   = 512;

// t_pre[t][j]: trace AFTER the step-t update (what stdp_step's dw uses).
__global__ __launch_bounds__(256)
void tp_precompute_kernel(const float* __restrict__ x, float* __restrict__ tp_ws) {
    const int j = blockIdx.x * blockDim.x + threadIdx.x;
    float tp = 0.f;
    #pragma unroll 16
    for (int t = 0; t < T_STEPS; ++t) {
        tp = fmaf(0.05f, x[t * N_IN + j] - tp, tp);
        tp_ws[t * N_IN + j] = tp;
    }
}

template <int CTRL, int RM>
__device__ __forceinline__ float dpp_add(float x) {
    int t = __builtin_amdgcn_update_dpp(0, __builtin_bit_cast(int, x),
                                        CTRL, RM, 0xF, true);
    return x + __builtin_bit_cast(float, t);
}

// Sum across 64 lanes; returns wave-uniform scalar (readlane 63 -> SGPR).
__device__ __forceinline__ float wave_sum64(float x) {
    x = dpp_add<0x111, 0xF>(x);   // row_shr:1
    x = dpp_add<0x112, 0xF>(x);   // row_shr:2
    x = dpp_add<0x114, 0xF>(x);   // row_shr:4
    x = dpp_add<0x118, 0xF>(x);   // row_shr:8
    x = dpp_add<0x142, 0xA>(x);   // row_bcast:15 -> rows 1,3
    x = dpp_add<0x143, 0xC>(x);   // row_bcast:31 -> rows 2,3
    return __builtin_bit_cast(float,
        __builtin_amdgcn_readlane(__builtin_bit_cast(int, x), 63));
}

__device__ __forceinline__ float clamp01(float x) {
    return __builtin_amdgcn_fmed3f(x, 0.f, 1.f);   // folds to clamp bit
}

__global__ __launch_bounds__(256, 2)
void snn_exc_kernel(const float* __restrict__ x,     // [T, N_IN]
                    const float* __restrict__ w0,    // [N_EXC, N_IN]
                    const float* __restrict__ tp_ws, // [T, N_IN]
                    float* __restrict__ out)         // [T, N_EXC]
{
    __shared__ float part[2][4][4];    // [buf][src wave][neuron], 128 B

    const int tid  = threadIdx.x;
    const int lane = tid & 63;
    const int wid  = tid >> 6;
    const int nb   = blockIdx.x * 4;   // 4 neurons per block

    // wave wid, lane l owns cols j = wid*512 + m*256 + l*4 + {0..3}, m=0..1
    float w[4][8];
    #pragma unroll
    for (int n = 0; n < 4; ++n) {
        const float4* wr = reinterpret_cast<const float4*>(
            w0 + (size_t)(nb + n) * N_IN + wid * SLICE);
        #pragma unroll
        for (int m = 0; m < 2; ++m) {
            float4 t4 = wr[m * 64 + lane];
            w[n][4*m+0] = t4.x; w[n][4*m+1] = t4.y;
            w[n][4*m+2] = t4.z; w[n][4*m+3] = t4.w;
        }
    }

    const float4* xsl = reinterpret_cast<const float4*>(x + wid * SLICE) + lane;
    const float4* tps = reinterpret_cast<const float4*>(tp_ws + wid * SLICE) + lane;

    if (tid < 32) reinterpret_cast<float*>(part)[tid] = 0.f;

    float4 xa0 = xsl[0], xa1 = xsl[64];          // x_0 slice
    float4 xb0 = xa0, xb1 = xa1;                 // (init silences warnings)
    __syncthreads();                             // publishes zeroed partials

    float v[4]     = {0.f, 0.f, 0.f, 0.f};
    float syn[4]   = {0.f, 0.f, 0.f, 0.f};
    float rho[4]   = {0.f, 0.f, 0.f, 0.f};
    float tpost[4] = {0.f, 0.f, 0.f, 0.f};

    auto step = [&](int t, float4& xc0, float4& xc1, float4& xn0, float4& xn1) {
        // ---- (1) read step-(t-1) partials (uniform addr -> broadcast) ----
        const float* pb = &part[t & 1][0][0];
        const float4 pA = *reinterpret_cast<const float4*>(pb + 0);
        const float4 pB = *reinterpret_cast<const float4*>(pb + 4);
        const float4 pC = *reinterpret_cast<const float4*>(pb + 8);
        const float4 pD = *reinterpret_cast<const float4*>(pb + 12);

        // ---- (2) prefetch x slice of row t+1 ----
        int tn = t + 1; if (tn > T_STEPS - 1) tn = T_STEPS - 1;
        const float4* xp = xsl + (size_t)tn * (N_IN / 4);
        xn0 = xp[0]; xn1 = xp[64];

        // ---- (3) complete syn with inp(t-1); LIF for all 4 neurons ----
        const float totn[4] = {
            (pA.x + pB.x) + (pC.x + pD.x),
            (pA.y + pB.y) + (pC.y + pD.y),
            (pA.z + pB.z) + (pC.z + pD.z),
            (pA.w + pB.w) + (pC.w + pD.w) };
        float z[4], c2[4];
        int sk[4];
        #pragma unroll
        for (int n = 0; n < 4; ++n) {
            syn[n] = fmaf(0.8f, syn[n], totn[n]);
            const float vd = fmaf(0.1f, syn[n] - v[n], v[n]);
            const bool rf = (rho[n] > 0.f);
            const bool s  = (vd > 1.0f) && !rf;
            v[n]   = (s || rf) ? 0.f : vd;
            rho[n] = s ? 5.0f : fmaxf(rho[n] - 1.0f, 0.f);
            z[n]   = s ? 1.f : 0.f;
            tpost[n] = fmaf(0.05f, z[n] - tpost[n], tpost[n]);
            c2[n]  = 1e-3f * tpost[n];
            sk[n]  = __builtin_amdgcn_readfirstlane((int)s);
        }

        // ---- (4) spike output: wave wid stores neuron wid ----
        const float zsel = (wid == 0) ? z[0] : (wid == 1) ? z[1]
                         : (wid == 2) ? z[2] : z[3];
        if (lane == 0) out[(size_t)t * N_EXC + nb + wid] = zsel;

        // ---- (5) t_pre slice load, only if some neuron spiked ----
        float4 tq0, tq1;
        if (sk[0] | sk[1] | sk[2] | sk[3]) {
            const float4* tp4 = tps + (size_t)t * (N_IN / 4);
            tq0 = tp4[0]; tq1 = tp4[64];
        }

        // ---- (6) 4 slice-dots (4 independent fma chains of depth 8) ----
        float acc[4];
        #pragma unroll
        for (int n = 0; n < 4; ++n) {
            float a =      xc0.x * w[n][0];
            a = fmaf(xc0.y, w[n][1], a);
            a = fmaf(xc0.z, w[n][2], a);
            a = fmaf(xc0.w, w[n][3], a);
            a = fmaf(xc1.x, w[n][4], a);
            a = fmaf(xc1.y, w[n][5], a);
            a = fmaf(xc1.z, w[n][6], a);
            a = fmaf(xc1.w, w[n][7], a);
            acc[n] = a;
        }

        // ---- (7) reduce + publish partials for step t+1 (latency hides
        //          under the STDP block below) ----
        const float r0 = wave_sum64(acc[0]);
        const float r1 = wave_sum64(acc[1]);
        const float r2 = wave_sum64(acc[2]);
        const float r3 = wave_sum64(acc[3]);
        if (lane == 0) {
            float4 pw; pw.x = r0; pw.y = r1; pw.z = r2; pw.w = r3;
            *reinterpret_cast<float4*>(&part[(t + 1) & 1][wid][0]) = pw;
        }

        // ---- (8) STDP updates (wave-uniform branches) ----
        #pragma unroll
        for (int n = 0; n < 4; ++n) {
            const float cc = c2[n];
            if (sk[n]) {
                w[n][0] = clamp01(fmaf(1e-3f, tq0.x, fmaf(-cc, xc0.x, w[n][0])));
                w[n][1] = clamp01(fmaf(1e-3f, tq0.y, fmaf(-cc, xc0.y, w[n][1])));
                w[n][2] = clamp01(fmaf(1e-3f, tq0.z, fmaf(-cc, xc0.z, w[n][2])));
                w[n][3] = clamp01(fmaf(1e-3f, tq0.w, fmaf(-cc, xc0.w, w[n][3])));
                w[n][4] = clamp01(fmaf(1e-3f, tq1.x, fmaf(-cc, xc1.x, w[n][4])));
                w[n][5] = clamp01(fmaf(1e-3f, tq1.y, fmaf(-cc, xc1.y, w[n][5])));
                w[n][6] = clamp01(fmaf(1e-3f, tq1.z, fmaf(-cc, xc1.z, w[n][6])));
                w[n][7] = clamp01(fmaf(1e-3f, tq1.w, fmaf(-cc, xc1.w, w[n][7])));
            } else {
                w[n][0] = clamp01(fmaf(-cc, xc0.x, w[n][0]));
                w[n][1] = clamp01(fmaf(-cc, xc0.y, w[n][1]));
                w[n][2] = clamp01(fmaf(-cc, xc0.z, w[n][2]));
                w[n][3] = clamp01(fmaf(-cc, xc0.w, w[n][3]));
                w[n][4] = clamp01(fmaf(-cc, xc1.x, w[n][4]));
                w[n][5] = clamp01(fmaf(-cc, xc1.y, w[n][5]));
                w[n][6] = clamp01(fmaf(-cc, xc1.z, w[n][6]));
                w[n][7] = clamp01(fmaf(-cc, xc1.w, w[n][7]));
            }
        }

        // ---- (9) one barrier: publishes part[(t+1)&1] for step t+1 ----
        __syncthreads();
    };

    for (int t = 0; t < T_STEPS; t += 2) {
        step(t,     xa0, xa1, xb0, xb1);
        step(t + 1, xb0, xb1, xa0, xa1);
    }
}

extern "C" void kernel_launch(void* const* d_in, const int* in_sizes, int n_in,
                              void* d_out, int out_size, void* d_ws, size_t ws_size,
                              hipStream_t stream) {
    const float* x  = (const float*)d_in[0];   // exc_currents [128, 2048] f32
    const float* w0 = (const float*)d_in[1];   // w_exc [2048, 2048] f32
    // d_in[2] (w_inh) unused: inhibitory layer does not affect the output
    float* out = (float*)d_out;                // spikes [128, 2048] f32

    float* tp_ws = (float*)d_ws;               // 1 MiB, ws_size is ample
    tp_precompute_kernel<<<N_IN / 256, 256, 0, stream>>>(x, tp_ws);

    dim3 grid(N_EXC / 4);                      // 512 blocks, 2 blocks/CU
    dim3 block(256);                           // 4 waves, each 512-col slice
    snn_exc_kernel<<<grid, block, 0, stream>>>(x, w0, tp_ws, out);
}

// Round 11
// 90.743 us; speedup vs baseline: 1.5285x; 1.5285x over previous
//
#include <hip/hip_runtime.h>

// SNN excitatory layer only (inhibitory layer never affects the returned
// spikes — the scan discards its carry).
//
// R10 "variant A": 2 neurons x 1024 cols per wave.
//  - keeps 2048 waves (2/SIMD TLP, same as the 95us baseline) while halving
//    per-CU x traffic through L1 (64 -> 32 KB/step): each x value loaded
//    once per wave feeds TWO dot products and TWO STDP updates.
//  - block = 4 waves = 2 neuron-pairs x 2 column-halves; the two halves of
//    a pair exchange partial sums via 16 floats of LDS, double-buffered,
//    one barrier/step; partial(t) is consumed at t+1's syn update (R3
//    insight) so the exchange has a full step of slack.
//  - reduce: DPP tree to lane 63 only (no readlane); lane 63 ds_writes both
//    neurons' partials as one b64. LIF consumes partials from LDS.
//  - dot chains / half-sum order / LIF / STDP arithmetic replicate the
//    passing R4 kernel exactly.

constexpr int T_STEPS = 128;
constexpr int N_IN    = 2048;
constexpr int N_EXC   = 2048;
constexpr int HALF    = 1024;

// t_pre[t][j]: trace AFTER the step-t update (what stdp_step's dw uses).
__global__ __launch_bounds__(256)
void tp_precompute_kernel(const float* __restrict__ x, float* __restrict__ tp_ws) {
    const int j = blockIdx.x * blockDim.x + threadIdx.x;
    float tp = 0.f;
    #pragma unroll 16
    for (int t = 0; t < T_STEPS; ++t) {
        tp = fmaf(0.05f, x[t * N_IN + j] - tp, tp);
        tp_ws[t * N_IN + j] = tp;
    }
}

template <int CTRL, int RM>
__device__ __forceinline__ float dpp_add(float x) {
    int t = __builtin_amdgcn_update_dpp(0, __builtin_bit_cast(int, x),
                                        CTRL, RM, 0xF, true);
    return x + __builtin_bit_cast(float, t);
}

// After this chain, lane 63 holds the 64-lane sum (no readlane).
__device__ __forceinline__ float wave_sum64_to_lane63(float x) {
    x = dpp_add<0x111, 0xF>(x);   // row_shr:1
    x = dpp_add<0x112, 0xF>(x);   // row_shr:2
    x = dpp_add<0x114, 0xF>(x);   // row_shr:4
    x = dpp_add<0x118, 0xF>(x);   // row_shr:8
    x = dpp_add<0x142, 0xA>(x);   // row_bcast:15 -> rows 1,3
    x = dpp_add<0x143, 0xC>(x);   // row_bcast:31 -> rows 2,3
    return x;
}

__device__ __forceinline__ float clamp01(float x) {
    return __builtin_amdgcn_fmed3f(x, 0.f, 1.f);   // folds to clamp bit
}

__global__ __launch_bounds__(256, 2)
void snn_exc_kernel(const float* __restrict__ x,     // [T, N_IN]
                    const float* __restrict__ w0,    // [N_EXC, N_IN]
                    const float* __restrict__ tp_ws, // [T, N_IN]
                    float* __restrict__ out)         // [T, N_EXC]
{
    // part[buf][pair][half][neuron]: lane63 of wave (p,h) writes {A,B} as b64;
    // wave (p,*) reads its 4 floats {A0,B0,A1,B1} as one b128.
    __shared__ float part[2][2][2][2];               // 64 B

    const int tid  = threadIdx.x;
    const int lane = tid & 63;
    const int wid  = tid >> 6;
    const int p    = wid >> 1;          // neuron pair within block
    const int h    = wid & 1;           // column half
    const int rA   = blockIdx.x * 4 + 2 * p;   // rows rA, rA+1

    // lane l owns cols j = h*1024 + m*256 + l*4 + {0..3}, m = 0..3
    float wA[16], wB[16];
    {
        const float4* ra = reinterpret_cast<const float4*>(w0 + (size_t)rA * N_IN + h * HALF);
        const float4* rb = reinterpret_cast<const float4*>(w0 + (size_t)(rA + 1) * N_IN + h * HALF);
        #pragma unroll
        for (int m = 0; m < 4; ++m) {
            float4 a = ra[m * 64 + lane];
            float4 b = rb[m * 64 + lane];
            wA[4*m+0] = a.x; wA[4*m+1] = a.y; wA[4*m+2] = a.z; wA[4*m+3] = a.w;
            wB[4*m+0] = b.x; wB[4*m+1] = b.y; wB[4*m+2] = b.z; wB[4*m+3] = b.w;
        }
    }

    const float4* xsl = reinterpret_cast<const float4*>(x + h * HALF) + lane;
    const float4* tps = reinterpret_cast<const float4*>(tp_ws + h * HALF) + lane;

    if (tid < 16) reinterpret_cast<float*>(part)[tid] = 0.f;

    float4 xa[4], xb[4];
    #pragma unroll
    for (int m = 0; m < 4; ++m) xa[m] = xsl[m * 64];   // x_0 slice
    __syncthreads();                                   // publishes zeroed part

    float vA = 0.f, synA = 0.f, rhoA = 0.f, tpostA = 0.f;
    float vB = 0.f, synB = 0.f, rhoB = 0.f, tpostB = 0.f;

    auto step = [&](int t, const float4 (&xc)[4], float4 (&xn)[4]) {
        // ---- (1) prefetch x slice of row t+1 ----
        int tn = t + 1; if (tn > T_STEPS - 1) tn = T_STEPS - 1;
        const float4* xp = xsl + (size_t)tn * (N_IN / 4);
        #pragma unroll
        for (int m = 0; m < 4; ++m) xn[m] = xp[m * 64];

        // ---- (2) read step-(t-1) partials {A0,B0,A1,B1}; complete syn ----
        const float4 pp = *reinterpret_cast<const float4*>(&part[t & 1][p][0][0]);
        synA = fmaf(0.8f, synA, pp.x + pp.z);
        synB = fmaf(0.8f, synB, pp.y + pp.w);

        // ---- (3) LIF both neurons (spike known before the dot) ----
        const float vdA = fmaf(0.1f, synA - vA, vA);
        const bool  rfA = (rhoA > 0.f);
        const bool  kA  = (vdA > 1.0f) && !rfA;
        vA     = (kA || rfA) ? 0.f : vdA;
        rhoA   = kA ? 5.0f : fmaxf(rhoA - 1.0f, 0.f);
        const float zA = kA ? 1.f : 0.f;
        tpostA = fmaf(0.05f, zA - tpostA, tpostA);
        const float c2A = 1e-3f * tpostA;

        const float vdB = fmaf(0.1f, synB - vB, vB);
        const bool  rfB = (rhoB > 0.f);
        const bool  kB  = (vdB > 1.0f) && !rfB;
        vB     = (kB || rfB) ? 0.f : vdB;
        rhoB   = kB ? 5.0f : fmaxf(rhoB - 1.0f, 0.f);
        const float zB = kB ? 1.f : 0.f;
        tpostB = fmaf(0.05f, zB - tpostB, tpostB);
        const float c2B = 1e-3f * tpostB;

        if (h == 0 && lane == 0) {
            float2 zz; zz.x = zA; zz.y = zB;
            *reinterpret_cast<float2*>(out + (size_t)t * N_EXC + rA) = zz;
        }

        const int sA = __builtin_amdgcn_readfirstlane((int)kA);
        const int sB = __builtin_amdgcn_readfirstlane((int)kB);

        // ---- (4) t_pre slice, only if either neuron spiked ----
        float4 tq[4];
        if (sA | sB) {
            const float4* tp4 = tps + (size_t)t * (N_IN / 4);
            #pragma unroll
            for (int m = 0; m < 4; ++m) tq[m] = tp4[m * 64];
        }

        // ---- (5) two dots over PRE-update w (x reused from registers) ----
        float a0 = 0.f, a1 = 0.f, a2 = 0.f, a3 = 0.f;
        float b0 = 0.f, b1 = 0.f, b2 = 0.f, b3 = 0.f;
        #pragma unroll
        for (int m = 0; m < 4; ++m) {
            a0 = fmaf(xc[m].x, wA[4*m+0], a0);
            b0 = fmaf(xc[m].x, wB[4*m+0], b0);
            a1 = fmaf(xc[m].y, wA[4*m+1], a1);
            b1 = fmaf(xc[m].y, wB[4*m+1], b1);
            a2 = fmaf(xc[m].z, wA[4*m+2], a2);
            b2 = fmaf(xc[m].z, wB[4*m+2], b2);
            a3 = fmaf(xc[m].w, wA[4*m+3], a3);
            b3 = fmaf(xc[m].w, wB[4*m+3], b3);
        }

        // ---- (6) reduce to lane 63; publish both partials as one b64 ----
        const float sAr = wave_sum64_to_lane63((a0 + a1) + (a2 + a3));
        const float sBr = wave_sum64_to_lane63((b0 + b1) + (b2 + b3));
        if (lane == 63) {
            float2 pw; pw.x = sAr; pw.y = sBr;
            *reinterpret_cast<float2*>(&part[(t + 1) & 1][p][h][0]) = pw;
        }

        // ---- (7) STDP updates (wave-uniform branches) ----
        if (sA) {
            #pragma unroll
            for (int m = 0; m < 4; ++m) {
                wA[4*m+0] = clamp01(fmaf(1e-3f, tq[m].x, fmaf(-c2A, xc[m].x, wA[4*m+0])));
                wA[4*m+1] = clamp01(fmaf(1e-3f, tq[m].y, fmaf(-c2A, xc[m].y, wA[4*m+1])));
                wA[4*m+2] = clamp01(fmaf(1e-3f, tq[m].z, fmaf(-c2A, xc[m].z, wA[4*m+2])));
                wA[4*m+3] = clamp01(fmaf(1e-3f, tq[m].w, fmaf(-c2A, xc[m].w, wA[4*m+3])));
            }
        } else {
            #pragma unroll
            for (int m = 0; m < 4; ++m) {
                wA[4*m+0] = clamp01(fmaf(-c2A, xc[m].x, wA[4*m+0]));
                wA[4*m+1] = clamp01(fmaf(-c2A, xc[m].y, wA[4*m+1]));
                wA[4*m+2] = clamp01(fmaf(-c2A, xc[m].z, wA[4*m+2]));
                wA[4*m+3] = clamp01(fmaf(-c2A, xc[m].w, wA[4*m+3]));
            }
        }
        if (sB) {
            #pragma unroll
            for (int m = 0; m < 4; ++m) {
                wB[4*m+0] = clamp01(fmaf(1e-3f, tq[m].x, fmaf(-c2B, xc[m].x, wB[4*m+0])));
                wB[4*m+1] = clamp01(fmaf(1e-3f, tq[m].y, fmaf(-c2B, xc[m].y, wB[4*m+1])));
                wB[4*m+2] = clamp01(fmaf(1e-3f, tq[m].z, fmaf(-c2B, xc[m].z, wB[4*m+2])));
                wB[4*m+3] = clamp01(fmaf(1e-3f, tq[m].w, fmaf(-c2B, xc[m].w, wB[4*m+3])));
            }
        } else {
            #pragma unroll
            for (int m = 0; m < 4; ++m) {
                wB[4*m+0] = clamp01(fmaf(-c2B, xc[m].x, wB[4*m+0]));
                wB[4*m+1] = clamp01(fmaf(-c2B, xc[m].y, wB[4*m+1]));
                wB[4*m+2] = clamp01(fmaf(-c2B, xc[m].z, wB[4*m+2]));
                wB[4*m+3] = clamp01(fmaf(-c2B, xc[m].w, wB[4*m+3]));
            }
        }

        // ---- (8) one barrier: publishes part[(t+1)&1] for step t+1 ----
        __syncthreads();
    };

    for (int t = 0; t < T_STEPS; t += 2) {
        step(t,     xa, xb);
        step(t + 1, xb, xa);
    }
}

extern "C" void kernel_launch(void* const* d_in, const int* in_sizes, int n_in,
                              void* d_out, int out_size, void* d_ws, size_t ws_size,
                              hipStream_t stream) {
    const float* x  = (const float*)d_in[0];   // exc_currents [128, 2048] f32
    const float* w0 = (const float*)d_in[1];   // w_exc [2048, 2048] f32
    // d_in[2] (w_inh) unused: inhibitory layer does not affect the output
    float* out = (float*)d_out;                // spikes [128, 2048] f32

    float* tp_ws = (float*)d_ws;               // 1 MiB, ws_size is ample
    tp_precompute_kernel<<<N_IN / 256, 256, 0, stream>>>(x, tp_ws);

    dim3 grid(N_EXC / 4);                      // 512 blocks, 2 blocks/CU
    dim3 block(256);                           // 4 waves = 2 pairs x 2 halves
    snn_exc_kernel<<<grid, block, 0, stream>>>(x, w0, tp_ws, out);
}